// Round 1
// baseline (1574.160 us; speedup 1.0000x reference)
//
#include <hip/hip_runtime.h>
#include <hip/hip_bf16.h>

typedef _Float16 f16x8 __attribute__((ext_vector_type(8)));
typedef float f32x4 __attribute__((ext_vector_type(4)));

#define MFMA16(A, B, C) __builtin_amdgcn_mfma_f32_16x16x32_f16((A), (B), (C), 0, 0, 0)

#define DIMD 512
#define SEQ  8192
#define MTOT 16384  // 2*8192 rows

// ---------------------------------------------------------------------------
// Projection GEMM: out[m][e] = sum_d x1[m][d] * W[e][d] + b[e], fp16 output.
// 128x128 tile, BK=32, 4 waves each 64x64 (4x4 of 16x16x32 f16 MFMA).
// ---------------------------------------------------------------------------
__global__ __launch_bounds__(256) void proj_kernel(
    const float* __restrict__ x1,
    const float* __restrict__ Wk, const float* __restrict__ bk,
    const float* __restrict__ Wq, const float* __restrict__ bq,
    const float* __restrict__ Wv, const float* __restrict__ bv,
    _Float16* __restrict__ Kh, _Float16* __restrict__ Qh, _Float16* __restrict__ Vh)
{
    const int g = blockIdx.z;
    const float* W    = (g == 0) ? Wk : (g == 1) ? Wq : Wv;
    const float* bias = (g == 0) ? bk : (g == 1) ? bq : bv;
    _Float16* outp    = (g == 0) ? Kh : (g == 1) ? Qh : Vh;

    const int m0 = blockIdx.x * 128;
    const int n0 = blockIdx.y * 128;
    const int t  = threadIdx.x;
    const int lane = t & 63;
    const int w  = t >> 6;
    const int wr = w >> 1, wc = w & 1;
    const int lr = lane & 15;          // fragment row/col within 16
    const int lk = (lane >> 4) * 8;    // k-offset (8 contiguous f16)

    // +8 f16 pad (16B) keeps 16B alignment, breaks bank conflicts
    __shared__ _Float16 Ah[128][40];
    __shared__ _Float16 Bh[128][40];

    f32x4 acc[4][4] = {};

    const int sr  = t >> 1;            // staging row 0..127
    const int skh = (t & 1) * 16;      // k-half 0 or 16

    for (int k0 = 0; k0 < DIMD; k0 += 32) {
        const float* sa = x1 + (size_t)(m0 + sr) * DIMD + k0 + skh;
        const float* sb = W  + (size_t)(n0 + sr) * DIMD + k0 + skh;
        _Float16 ta[16], tb[16];
        #pragma unroll
        for (int i = 0; i < 4; i++) {
            f32x4 va = *(const f32x4*)(sa + i * 4);
            f32x4 vb = *(const f32x4*)(sb + i * 4);
            #pragma unroll
            for (int u = 0; u < 4; u++) {
                ta[i * 4 + u] = (_Float16)va[u];
                tb[i * 4 + u] = (_Float16)vb[u];
            }
        }
        __syncthreads();   // previous compute done before overwriting LDS
        *(f16x8*)&Ah[sr][skh]     = *(f16x8*)&ta[0];
        *(f16x8*)&Ah[sr][skh + 8] = *(f16x8*)&ta[8];
        *(f16x8*)&Bh[sr][skh]     = *(f16x8*)&tb[0];
        *(f16x8*)&Bh[sr][skh + 8] = *(f16x8*)&tb[8];
        __syncthreads();   // staging visible

        f16x8 af[4], bf[4];
        #pragma unroll
        for (int i = 0; i < 4; i++) af[i] = *(const f16x8*)&Ah[wr * 64 + i * 16 + lr][lk];
        #pragma unroll
        for (int j = 0; j < 4; j++) bf[j] = *(const f16x8*)&Bh[wc * 64 + j * 16 + lr][lk];
        #pragma unroll
        for (int i = 0; i < 4; i++)
            #pragma unroll
            for (int j = 0; j < 4; j++)
                acc[i][j] = MFMA16(af[i], bf[j], acc[i][j]);
    }

    // epilogue: bias add, cvt fp16, store. D layout: col=lr, row=(lane>>4)*4+jj
    const int col0 = n0 + wc * 64;
    const int row0 = m0 + wr * 64;
    #pragma unroll
    for (int j = 0; j < 4; j++) {
        float bval = bias[col0 + j * 16 + lr];
        #pragma unroll
        for (int i = 0; i < 4; i++) {
            #pragma unroll
            for (int jj = 0; jj < 4; jj++) {
                int mrow = row0 + i * 16 + (lane >> 4) * 4 + jj;
                outp[(size_t)mrow * DIMD + col0 + j * 16 + lr] =
                    (_Float16)(acc[i][j][jj] + bval);
            }
        }
    }
}

// ---------------------------------------------------------------------------
// Flash attention with swapped roles: rows come from k (role-Q), columns/softmax
// axis from q (role-K), values v (role-V). No 1/sqrt(d) scale (faithful to ref).
// Block: 64 q-rows (4 waves x 16 rows), KV tile = 32, D = 512.
// ---------------------------------------------------------------------------
__global__ __launch_bounds__(256) void flash_kernel(
    const _Float16* __restrict__ Kh,   // role-Q (rows of output)
    const _Float16* __restrict__ Qh,   // role-K (softmax axis)
    const _Float16* __restrict__ Vh,   // role-V
    float* __restrict__ out)
{
    const int qb = blockIdx.x;          // 0..127
    const int b  = blockIdx.y;          // 0..1
    const size_t boff = (size_t)b * SEQ * DIMD;
    const int t    = threadIdx.x;
    const int lane = t & 63;
    const int w    = t >> 6;
    const int lr   = lane & 15;
    const int lkg  = lane >> 4;         // 0..3
    const int lk   = lkg * 8;

    __shared__ _Float16 Klds[32][520];     // role-K tile, row-major, +16B pad
    __shared__ _Float16 Vlds[512][40];     // role-V tile TRANSPOSED [d][kv], pad
    __shared__ _Float16 Plds[4][16][40];   // per-wave P tile [q][kv]

    // role-Q fragments in registers: wave's 16 rows x 512
    const int qrow = qb * 64 + w * 16 + lr;
    f16x8 qf[16];
    #pragma unroll
    for (int ks = 0; ks < 16; ks++)
        qf[ks] = *(const f16x8*)(Kh + boff + (size_t)qrow * DIMD + ks * 32 + lk);

    f32x4 Oacc[32] = {};
    float m_[4], l_[4];
    #pragma unroll
    for (int j = 0; j < 4; j++) { m_[j] = -1e30f; l_[j] = 0.f; }

    const int skv = t >> 3;             // staging kv row 0..31
    const int sck = (t & 7) * 64;       // staging d-chunk base

    for (int it = 0; it < SEQ / 32; ++it) {
        const int t0 = it * 32;
        // ---- stage role-K (row-major) and role-V (transposed) ----
        #pragma unroll
        for (int i = 0; i < 8; i++) {
            f16x8 kv8 = *(const f16x8*)(Qh + boff + (size_t)(t0 + skv) * DIMD + sck + i * 8);
            *(f16x8*)&Klds[skv][sck + i * 8] = kv8;
            f16x8 vv8 = *(const f16x8*)(Vh + boff + (size_t)(t0 + skv) * DIMD + sck + i * 8);
            #pragma unroll
            for (int u = 0; u < 8; u++) Vlds[sck + i * 8 + u][skv] = vv8[u];
        }
        __syncthreads();

        // ---- QK^T: S[16 q][32 kv], two 16x16 n-tiles ----
        f32x4 s0 = {}, s1 = {};
        #pragma unroll
        for (int ks = 0; ks < 16; ks++) {
            f16x8 b0 = *(const f16x8*)&Klds[lr][ks * 32 + lk];
            f16x8 b1 = *(const f16x8*)&Klds[16 + lr][ks * 32 + lk];
            s0 = MFMA16(qf[ks], b0, s0);
            s1 = MFMA16(qf[ks], b1, s1);
        }

        // ---- online softmax (rows = 4*lkg+j, cols kv = lr / lr+16) ----
        float tm[4];
        #pragma unroll
        for (int j = 0; j < 4; j++) tm[j] = fmaxf(s0[j], s1[j]);
        #pragma unroll
        for (int off = 1; off < 16; off <<= 1)
            #pragma unroll
            for (int j = 0; j < 4; j++)
                tm[j] = fmaxf(tm[j], __shfl_xor(tm[j], off, 64));

        float pr0[4], pr1[4], scale[4], ps[4];
        #pragma unroll
        for (int j = 0; j < 4; j++) {
            float nm = fmaxf(m_[j], tm[j]);
            scale[j] = __expf(m_[j] - nm);
            m_[j] = nm;
            pr0[j] = __expf(s0[j] - nm);
            pr1[j] = __expf(s1[j] - nm);
            ps[j] = pr0[j] + pr1[j];
        }
        #pragma unroll
        for (int off = 1; off < 16; off <<= 1)
            #pragma unroll
            for (int j = 0; j < 4; j++)
                ps[j] += __shfl_xor(ps[j], off, 64);
        #pragma unroll
        for (int j = 0; j < 4; j++) l_[j] = l_[j] * scale[j] + ps[j];

        int need = (scale[0] != 1.f) | (scale[1] != 1.f) |
                   (scale[2] != 1.f) | (scale[3] != 1.f);
        if (__any(need)) {
            #pragma unroll
            for (int dt = 0; dt < 32; dt++)
                #pragma unroll
                for (int j = 0; j < 4; j++) Oacc[dt][j] *= scale[j];
        }

        // ---- write P (fp16) to per-wave LDS; same-wave DS is in-order ----
        #pragma unroll
        for (int j = 0; j < 4; j++) {
            Plds[w][4 * lkg + j][lr]      = (_Float16)pr0[j];
            Plds[w][4 * lkg + j][lr + 16] = (_Float16)pr1[j];
        }

        // ---- PV: O[16 q][512 d] += P[16x32] @ V[32 x 512] ----
        f16x8 pa = *(const f16x8*)&Plds[w][lr][lk];
        #pragma unroll
        for (int dt = 0; dt < 32; dt++) {
            f16x8 vb = *(const f16x8*)&Vlds[dt * 16 + lr][lk];
            Oacc[dt] = MFMA16(pa, vb, Oacc[dt]);
        }
        __syncthreads();   // protect K/V LDS before next staging
    }

    // ---- final normalize + store f32 ----
    float inv[4];
    #pragma unroll
    for (int j = 0; j < 4; j++) inv[j] = 1.0f / l_[j];
    #pragma unroll
    for (int dt = 0; dt < 32; dt++) {
        #pragma unroll
        for (int j = 0; j < 4; j++) {
            int srow = qb * 64 + w * 16 + 4 * lkg + j;
            out[boff + (size_t)srow * DIMD + dt * 16 + lr] = Oacc[dt][j] * inv[j];
        }
    }
}

extern "C" void kernel_launch(void* const* d_in, const int* in_sizes, int n_in,
                              void* d_out, int out_size, void* d_ws, size_t ws_size,
                              hipStream_t stream) {
    (void)in_sizes; (void)n_in; (void)out_size; (void)ws_size;
    const float* x1 = (const float*)d_in[0];
    const float* Wk = (const float*)d_in[1];
    const float* bk = (const float*)d_in[2];
    const float* Wq = (const float*)d_in[3];
    const float* bq = (const float*)d_in[4];
    const float* Wv = (const float*)d_in[5];
    const float* bv = (const float*)d_in[6];
    float* out = (float*)d_out;

    _Float16* Kh = (_Float16*)d_ws;
    _Float16* Qh = Kh + (size_t)MTOT * DIMD;
    _Float16* Vh = Qh + (size_t)MTOT * DIMD;

    // mask output: 16 zero floats after the attention output
    hipMemsetAsync((char*)d_out + (size_t)MTOT * DIMD * sizeof(float), 0, 64, stream);

    dim3 pg(128, 4, 3);
    proj_kernel<<<pg, 256, 0, stream>>>(x1, Wk, bk, Wq, bq, Wv, bv, Kh, Qh, Vh);

    dim3 fg(128, 2);
    flash_kernel<<<fg, 256, 0, stream>>>(Kh, Qh, Vh, out);
}

// Round 2
// 1168.466 us; speedup vs baseline: 1.3472x; 1.3472x over previous
//
#include <hip/hip_runtime.h>
#include <hip/hip_bf16.h>

typedef _Float16 f16x8 __attribute__((ext_vector_type(8)));
typedef float f32x4 __attribute__((ext_vector_type(4)));

#define MFMA16(A, B, C) __builtin_amdgcn_mfma_f32_16x16x32_f16((A), (B), (C), 0, 0, 0)

#define DIMD 512
#define SEQ  8192
#define MTOT 16384  // 2*8192 rows

#define GLOAD16(gp, lp) __builtin_amdgcn_global_load_lds( \
    (const __attribute__((address_space(1))) void*)(gp),  \
    (__attribute__((address_space(3))) void*)(lp), 16, 0, 0)

// ---------------------------------------------------------------------------
// Projection GEMM: out[m][e] = sum_d x1[m][d] * W[e][d] + b[e], fp16 output.
// g==2 (V) is stored TRANSPOSED: Vt[b][e][s].
// ---------------------------------------------------------------------------
__global__ __launch_bounds__(256) void proj_kernel(
    const float* __restrict__ x1,
    const float* __restrict__ Wk, const float* __restrict__ bk,
    const float* __restrict__ Wq, const float* __restrict__ bq,
    const float* __restrict__ Wv, const float* __restrict__ bv,
    _Float16* __restrict__ Kh, _Float16* __restrict__ Qh, _Float16* __restrict__ Vt)
{
    const int g = blockIdx.z;
    const float* W    = (g == 0) ? Wk : (g == 1) ? Wq : Wv;
    const float* bias = (g == 0) ? bk : (g == 1) ? bq : bv;

    const int m0 = blockIdx.x * 128;
    const int n0 = blockIdx.y * 128;
    const int t  = threadIdx.x;
    const int lane = t & 63;
    const int w  = t >> 6;
    const int wr = w >> 1, wc = w & 1;
    const int lr = lane & 15;
    const int lkg = lane >> 4;
    const int lk = lkg * 8;

    __shared__ _Float16 Ah[128][40];
    __shared__ _Float16 Bh[128][40];

    f32x4 acc[4][4] = {};

    const int sr  = t >> 1;
    const int skh = (t & 1) * 16;

    for (int k0 = 0; k0 < DIMD; k0 += 32) {
        const float* sa = x1 + (size_t)(m0 + sr) * DIMD + k0 + skh;
        const float* sb = W  + (size_t)(n0 + sr) * DIMD + k0 + skh;
        _Float16 ta[16], tb[16];
        #pragma unroll
        for (int i = 0; i < 4; i++) {
            f32x4 va = *(const f32x4*)(sa + i * 4);
            f32x4 vb = *(const f32x4*)(sb + i * 4);
            #pragma unroll
            for (int u = 0; u < 4; u++) {
                ta[i * 4 + u] = (_Float16)va[u];
                tb[i * 4 + u] = (_Float16)vb[u];
            }
        }
        __syncthreads();
        *(f16x8*)&Ah[sr][skh]     = *(f16x8*)&ta[0];
        *(f16x8*)&Ah[sr][skh + 8] = *(f16x8*)&ta[8];
        *(f16x8*)&Bh[sr][skh]     = *(f16x8*)&tb[0];
        *(f16x8*)&Bh[sr][skh + 8] = *(f16x8*)&tb[8];
        __syncthreads();

        f16x8 af[4], bf[4];
        #pragma unroll
        for (int i = 0; i < 4; i++) af[i] = *(const f16x8*)&Ah[wr * 64 + i * 16 + lr][lk];
        #pragma unroll
        for (int j = 0; j < 4; j++) bf[j] = *(const f16x8*)&Bh[wc * 64 + j * 16 + lr][lk];
        #pragma unroll
        for (int i = 0; i < 4; i++)
            #pragma unroll
            for (int j = 0; j < 4; j++)
                acc[i][j] = MFMA16(af[i], bf[j], acc[i][j]);
    }

    const int col0 = n0 + wc * 64;
    const int row0 = m0 + wr * 64;
    #pragma unroll
    for (int j = 0; j < 4; j++) {
        float bval = bias[col0 + j * 16 + lr];
        #pragma unroll
        for (int i = 0; i < 4; i++) {
            #pragma unroll
            for (int jj = 0; jj < 4; jj++) {
                int mrow = row0 + i * 16 + lkg * 4 + jj;
                int e    = col0 + j * 16 + lr;
                float val = acc[i][j][jj] + bval;
                if (g == 2) {
                    // transposed store: Vt[b][e][s]
                    Vt[(size_t)(mrow >> 13) * DIMD * SEQ + (size_t)e * SEQ + (mrow & 8191)] =
                        (_Float16)val;
                } else {
                    _Float16* outp = (g == 0) ? Kh : Qh;
                    outp[(size_t)mrow * DIMD + e] = (_Float16)val;
                }
            }
        }
    }
}

// ---------------------------------------------------------------------------
// Flash attention, swapped roles (rows from k, softmax axis from q, values v).
// Block: 64 rows. QK^T: wave w owns rows 16w..16w+15 (Q in regs, K from LDS).
// PV: d-sliced — wave w computes O[all 64 rows][128-wide d slice], V read once
// per block. P + scale + 1/l shared through LDS. KV split across blockIdx.y.
// ---------------------------------------------------------------------------
template<int SPLIT>
__global__ __launch_bounds__(256, 2) void flash_kernel(
    const _Float16* __restrict__ Kh,   // role-Q rows
    const _Float16* __restrict__ Qh,   // role-K (softmax axis)
    const _Float16* __restrict__ Vt,   // role-V transposed [2][512][8192]
    float* __restrict__ out,           // SPLIT==1 path
    _Float16* __restrict__ Opart,      // [SPLIT][MTOT][512]  (normalized, fp16)
    float* __restrict__ Ml)            // [SPLIT][MTOT][2]  (m, l)
{
    const int qb   = blockIdx.x;        // 0..255
    const int half = blockIdx.y;        // 0..SPLIT-1
    const int R0   = qb * 64;
    const int b    = R0 >> 13;
    const int t    = threadIdx.x;
    const int lane = t & 63;
    const int w    = t >> 6;
    const int lr   = lane & 15;
    const int lkg  = lane >> 4;

    __shared__ _Float16 Klds[32 * 512];   // role-K tile, rows XOR-swizzled (16B chunks)
    __shared__ _Float16 Vlds[512 * 32];   // V^T tile: [d][32 kv], 64B rows
    __shared__ _Float16 Plds[64 * 32];    // P tile [q][kv]
    __shared__ float    Scl[64];          // per-row scale / 1/l share

    const _Float16* Qb = Qh + (size_t)b * SEQ * DIMD;
    const _Float16* Vb = Vt + (size_t)b * DIMD * SEQ;

    // role-Q fragments in registers: wave's 16 rows x 512
    const int qrow = R0 + w * 16 + lr;
    f16x8 qf[16];
    #pragma unroll
    for (int ks = 0; ks < 16; ks++)
        qf[ks] = *(const f16x8*)(Kh + (size_t)qrow * DIMD + ks * 32 + lkg * 8);

    f32x4 Oacc[4][8] = {};
    float m_[4], l_[4];
    #pragma unroll
    for (int j = 0; j < 4; j++) { m_[j] = -1e30f; l_[j] = 0.f; }

    const int t0base = half * (SEQ / SPLIT);
    const int NT = (SEQ / SPLIT) / 32;

    // stage tile `it`: K rows swizzled, V^T rows linear; 16 x 1KB per wave
    #define STAGE(it)                                                          \
    {                                                                          \
        const int t0s = t0base + (it) * 32;                                    \
        _Pragma("unroll")                                                      \
        for (int i = 0; i < 8; i++) {                                          \
            const int r = w * 8 + i;                                           \
            const char* srcK = (const char*)(Qb + (size_t)(t0s + r) * DIMD)    \
                               + ((lane * 16) ^ (i << 4));                     \
            GLOAD16(srcK, (char*)Klds + r * 1024);                             \
        }                                                                      \
        _Pragma("unroll")                                                      \
        for (int i = 0; i < 8; i++) {                                          \
            const int d0 = (w * 8 + i) * 16;                                   \
            const _Float16* srcV = Vb + (size_t)(d0 + (lane >> 2)) * SEQ       \
                                   + t0s + 8 * (lane & 3);                     \
            GLOAD16(srcV, (char*)Vlds + d0 * 64);                              \
        }                                                                      \
    }

    STAGE(0);
    asm volatile("s_waitcnt vmcnt(0)" ::: "memory");
    __syncthreads();

    for (int it = 0; it < NT; ++it) {
        // ---- QK^T: wave's 16 rows x 32 kv ----
        f32x4 s0v = {}, s1v = {};
        #pragma unroll
        for (int ks = 0; ks < 16; ks++) {
            const int ch = (((ks * 4 + lkg) ^ (lr & 7)) << 4);
            f16x8 b0 = *(const f16x8*)((const char*)Klds + lr * 1024 + ch);
            f16x8 b1 = *(const f16x8*)((const char*)Klds + (lr + 16) * 1024 + ch);
            s0v = MFMA16(qf[ks], b0, s0v);
            s1v = MFMA16(qf[ks], b1, s1v);
        }

        // ---- online softmax (rows = 16w + 4*lkg + j, reduce across lr) ----
        float tm[4];
        #pragma unroll
        for (int j = 0; j < 4; j++) tm[j] = fmaxf(s0v[j], s1v[j]);
        #pragma unroll
        for (int off = 1; off < 16; off <<= 1)
            #pragma unroll
            for (int j = 0; j < 4; j++)
                tm[j] = fmaxf(tm[j], __shfl_xor(tm[j], off, 64));

        float pr0[4], pr1[4], scale[4], ps[4];
        #pragma unroll
        for (int j = 0; j < 4; j++) {
            float nm = fmaxf(m_[j], tm[j]);
            scale[j] = __expf(m_[j] - nm);
            m_[j] = nm;
            pr0[j] = __expf(s0v[j] - nm);
            pr1[j] = __expf(s1v[j] - nm);
            ps[j] = pr0[j] + pr1[j];
        }
        #pragma unroll
        for (int off = 1; off < 16; off <<= 1)
            #pragma unroll
            for (int j = 0; j < 4; j++)
                ps[j] += __shfl_xor(ps[j], off, 64);
        #pragma unroll
        for (int j = 0; j < 4; j++) l_[j] = l_[j] * scale[j] + ps[j];

        // share P (fp16) and per-row scale
        #pragma unroll
        for (int j = 0; j < 4; j++) {
            Plds[(16 * w + 4 * lkg + j) * 32 + lr]      = (_Float16)pr0[j];
            Plds[(16 * w + 4 * lkg + j) * 32 + lr + 16] = (_Float16)pr1[j];
        }
        if (lr == 0) {
            #pragma unroll
            for (int j = 0; j < 4; j++) Scl[16 * w + 4 * lkg + j] = scale[j];
        }
        __syncthreads();   // P + Scl visible; K reads done

        // ---- rescale O (rows = m*16 + lkg*4 + r) ----
        float sc[4][4]; int needv = 0;
        #pragma unroll
        for (int m = 0; m < 4; m++) {
            f32x4 s4 = *(const f32x4*)&Scl[m * 16 + lkg * 4];
            #pragma unroll
            for (int r = 0; r < 4; r++) { sc[m][r] = s4[r]; needv |= (s4[r] != 1.f); }
        }
        if (__any(needv)) {
            #pragma unroll
            for (int m = 0; m < 4; m++)
                #pragma unroll
                for (int n = 0; n < 8; n++)
                    #pragma unroll
                    for (int r = 0; r < 4; r++) Oacc[m][n][r] *= sc[m][r];
        }

        // ---- PV: O[64 q][d-slice 128w..] += P[64x32] @ V[32 x 128] ----
        f16x8 pa[4];
        #pragma unroll
        for (int m = 0; m < 4; m++)
            pa[m] = *(const f16x8*)&Plds[(m * 16 + lr) * 32 + lkg * 8];
        #pragma unroll
        for (int n = 0; n < 8; n++) {
            f16x8 vb = *(const f16x8*)&Vlds[(w * 128 + n * 16 + lr) * 32 + lkg * 8];
            #pragma unroll
            for (int m = 0; m < 4; m++)
                Oacc[m][n] = MFMA16(pa[m], vb, Oacc[m][n]);
        }
        __syncthreads();   // all waves done reading K/V/P

        if (it + 1 < NT) {
            STAGE(it + 1);
            asm volatile("s_waitcnt vmcnt(0)" ::: "memory");
            __syncthreads();   // staged data visible to all
        }
    }

    // ---- share 1/l (and m,l for SPLIT), normalize, store ----
    if (lr == 0) {
        #pragma unroll
        for (int j = 0; j < 4; j++) Scl[16 * w + 4 * lkg + j] = 1.f / l_[j];
        if (SPLIT > 1) {
            #pragma unroll
            for (int j = 0; j < 4; j++) {
                int R = R0 + 16 * w + 4 * lkg + j;
                Ml[((size_t)half * MTOT + R) * 2]     = m_[j];
                Ml[((size_t)half * MTOT + R) * 2 + 1] = l_[j];
            }
        }
    }
    __syncthreads();

    float li[4][4];
    #pragma unroll
    for (int m = 0; m < 4; m++) {
        f32x4 s4 = *(const f32x4*)&Scl[m * 16 + lkg * 4];
        #pragma unroll
        for (int r = 0; r < 4; r++) li[m][r] = s4[r];
    }
    #pragma unroll
    for (int m = 0; m < 4; m++) {
        #pragma unroll
        for (int n = 0; n < 8; n++) {
            #pragma unroll
            for (int r = 0; r < 4; r++) {
                float val = Oacc[m][n][r] * li[m][r];
                int R = R0 + m * 16 + lkg * 4 + r;
                int d = w * 128 + n * 16 + lr;
                if (SPLIT == 1) {
                    out[(size_t)R * DIMD + d] = val;
                } else {
                    Opart[((size_t)half * MTOT + R) * DIMD + d] = (_Float16)val;
                }
            }
        }
    }
    #undef STAGE
}

// ---------------------------------------------------------------------------
// Combine the SPLIT=2 halves: out = (a0*O0 + a1*O1), a_h = e^{m_h-M} l_h / Z
// ---------------------------------------------------------------------------
__global__ __launch_bounds__(256) void combine_kernel(
    const _Float16* __restrict__ Opart, const float* __restrict__ Ml,
    float* __restrict__ out)
{
    size_t idx = (size_t)blockIdx.x * 256 + threadIdx.x;
    size_t e0 = idx * 8;
    int R = (int)(e0 >> 9);
    float m0 = Ml[(size_t)R * 2],            l0 = Ml[(size_t)R * 2 + 1];
    float m1 = Ml[((size_t)MTOT + R) * 2],   l1 = Ml[((size_t)MTOT + R) * 2 + 1];
    float M  = fmaxf(m0, m1);
    float a0 = __expf(m0 - M) * l0;
    float a1 = __expf(m1 - M) * l1;
    float inv = 1.f / (a0 + a1);
    a0 *= inv; a1 *= inv;
    f16x8 o0 = *(const f16x8*)(Opart + e0);
    f16x8 o1 = *(const f16x8*)(Opart + (size_t)MTOT * DIMD + e0);
    f32x4 r0, r1;
    #pragma unroll
    for (int u = 0; u < 4; u++) r0[u] = a0 * (float)o0[u] + a1 * (float)o1[u];
    #pragma unroll
    for (int u = 0; u < 4; u++) r1[u] = a0 * (float)o0[u + 4] + a1 * (float)o1[u + 4];
    *(f32x4*)(out + e0) = r0;
    *(f32x4*)(out + e0 + 4) = r1;
}

extern "C" void kernel_launch(void* const* d_in, const int* in_sizes, int n_in,
                              void* d_out, int out_size, void* d_ws, size_t ws_size,
                              hipStream_t stream) {
    (void)in_sizes; (void)n_in; (void)out_size;
    const float* x1 = (const float*)d_in[0];
    const float* Wk = (const float*)d_in[1];
    const float* bk = (const float*)d_in[2];
    const float* Wq = (const float*)d_in[3];
    const float* bq = (const float*)d_in[4];
    const float* Wv = (const float*)d_in[5];
    const float* bv = (const float*)d_in[6];
    float* out = (float*)d_out;

    _Float16* Kh = (_Float16*)d_ws;
    _Float16* Qh = Kh + (size_t)MTOT * DIMD;
    _Float16* Vt = Qh + (size_t)MTOT * DIMD;

    const size_t base = (size_t)MTOT * DIMD * 2 * 3;   // 48 MB
    const size_t opart_bytes = (size_t)2 * MTOT * DIMD * sizeof(_Float16); // 32 MB
    const size_t need2 = base + opart_bytes + (size_t)2 * MTOT * 2 * sizeof(float);
    _Float16* Opart = (_Float16*)((char*)d_ws + base);
    float*    Ml    = (float*)((char*)d_ws + base + opart_bytes);
    const int split2 = (ws_size >= need2);

    // mask output: 16 zero floats after the attention output
    hipMemsetAsync((char*)d_out + (size_t)MTOT * DIMD * sizeof(float), 0, 64, stream);

    dim3 pg(128, 4, 3);
    proj_kernel<<<pg, 256, 0, stream>>>(x1, Wk, bk, Wq, bq, Wv, bv, Kh, Qh, Vt);

    if (split2) {
        flash_kernel<2><<<dim3(256, 2), 256, 0, stream>>>(Kh, Qh, Vt, out, Opart, Ml);
        combine_kernel<<<4096, 256, 0, stream>>>(Opart, Ml, out);
    } else {
        flash_kernel<1><<<dim3(256, 1), 256, 0, stream>>>(Kh, Qh, Vt, out, Opart, Ml);
    }
}

// Round 3
// 839.736 us; speedup vs baseline: 1.8746x; 1.3915x over previous
//
#include <hip/hip_runtime.h>
#include <hip/hip_bf16.h>

typedef _Float16 f16x8 __attribute__((ext_vector_type(8)));
typedef float f32x4 __attribute__((ext_vector_type(4)));

#define MFMA16(A, B, C) __builtin_amdgcn_mfma_f32_16x16x32_f16((A), (B), (C), 0, 0, 0)

#define DIMD 512
#define SEQ  8192
#define MTOT 16384  // 2*8192 rows

#define GLOAD16(gp, lp) __builtin_amdgcn_global_load_lds( \
    (const __attribute__((address_space(1))) void*)(gp),  \
    (__attribute__((address_space(3))) void*)(lp), 16, 0, 0)

// ---------------------------------------------------------------------------
// Projection GEMM: out[m][e] = sum_d x1[m][d] * W[e][d] + b[e], fp16 output.
// g==2 (V) is stored TRANSPOSED: Vt[b][e][s].
// ---------------------------------------------------------------------------
__global__ __launch_bounds__(256) void proj_kernel(
    const float* __restrict__ x1,
    const float* __restrict__ Wk, const float* __restrict__ bk,
    const float* __restrict__ Wq, const float* __restrict__ bq,
    const float* __restrict__ Wv, const float* __restrict__ bv,
    _Float16* __restrict__ Kh, _Float16* __restrict__ Qh, _Float16* __restrict__ Vt)
{
    const int g = blockIdx.z;
    const float* W    = (g == 0) ? Wk : (g == 1) ? Wq : Wv;
    const float* bias = (g == 0) ? bk : (g == 1) ? bq : bv;

    const int m0 = blockIdx.x * 128;
    const int n0 = blockIdx.y * 128;
    const int t  = threadIdx.x;
    const int lane = t & 63;
    const int w  = t >> 6;
    const int wr = w >> 1, wc = w & 1;
    const int lr = lane & 15;
    const int lkg = lane >> 4;
    const int lk = lkg * 8;

    __shared__ _Float16 Ah[128][40];
    __shared__ _Float16 Bh[128][40];

    f32x4 acc[4][4] = {};

    const int sr  = t >> 1;
    const int skh = (t & 1) * 16;

    for (int k0 = 0; k0 < DIMD; k0 += 32) {
        const float* sa = x1 + (size_t)(m0 + sr) * DIMD + k0 + skh;
        const float* sb = W  + (size_t)(n0 + sr) * DIMD + k0 + skh;
        _Float16 ta[16], tb[16];
        #pragma unroll
        for (int i = 0; i < 4; i++) {
            f32x4 va = *(const f32x4*)(sa + i * 4);
            f32x4 vb = *(const f32x4*)(sb + i * 4);
            #pragma unroll
            for (int u = 0; u < 4; u++) {
                ta[i * 4 + u] = (_Float16)va[u];
                tb[i * 4 + u] = (_Float16)vb[u];
            }
        }
        __syncthreads();
        *(f16x8*)&Ah[sr][skh]     = *(f16x8*)&ta[0];
        *(f16x8*)&Ah[sr][skh + 8] = *(f16x8*)&ta[8];
        *(f16x8*)&Bh[sr][skh]     = *(f16x8*)&tb[0];
        *(f16x8*)&Bh[sr][skh + 8] = *(f16x8*)&tb[8];
        __syncthreads();

        f16x8 af[4], bf[4];
        #pragma unroll
        for (int i = 0; i < 4; i++) af[i] = *(const f16x8*)&Ah[wr * 64 + i * 16 + lr][lk];
        #pragma unroll
        for (int j = 0; j < 4; j++) bf[j] = *(const f16x8*)&Bh[wc * 64 + j * 16 + lr][lk];
        #pragma unroll
        for (int i = 0; i < 4; i++)
            #pragma unroll
            for (int j = 0; j < 4; j++)
                acc[i][j] = MFMA16(af[i], bf[j], acc[i][j]);
    }

    const int col0 = n0 + wc * 64;
    const int row0 = m0 + wr * 64;
    #pragma unroll
    for (int j = 0; j < 4; j++) {
        float bval = bias[col0 + j * 16 + lr];
        #pragma unroll
        for (int i = 0; i < 4; i++) {
            #pragma unroll
            for (int jj = 0; jj < 4; jj++) {
                int mrow = row0 + i * 16 + lkg * 4 + jj;
                int e    = col0 + j * 16 + lr;
                float val = acc[i][j][jj] + bval;
                if (g == 2) {
                    Vt[(size_t)(mrow >> 13) * DIMD * SEQ + (size_t)e * SEQ + (mrow & 8191)] =
                        (_Float16)val;
                } else {
                    _Float16* outp = (g == 0) ? Kh : Qh;
                    outp[(size_t)mrow * DIMD + e] = (_Float16)val;
                }
            }
        }
    }
}

// ---------------------------------------------------------------------------
// Flash attention, swapped roles. 128 rows/block, 8 waves (512 thr), KVBLK=32,
// double-buffered K/V LDS, raw s_barrier (no mid-tile vmcnt drain),
// XCD-affinity block mapping so co-resident blocks share K/V tiles in L2.
// QK^T: wave w owns rows 16w..16w+15. PV: wave w owns d-slice [64w,64w+64).
// ---------------------------------------------------------------------------
template<int SPLIT>
__global__ __launch_bounds__(512, 2) void flash_kernel(
    const _Float16* __restrict__ Kh,   // role-Q rows
    const _Float16* __restrict__ Qh,   // role-K (softmax axis)
    const _Float16* __restrict__ Vt,   // role-V transposed [2][512][8192]
    float* __restrict__ out,           // SPLIT==1 path
    _Float16* __restrict__ Opart,      // [SPLIT][MTOT][512]  (normalized, fp16)
    float* __restrict__ Ml)            // [SPLIT][MTOT][2]  (m, l)
{
    const int B   = blockIdx.x;
    const int xcd = B & 7;
    constexpr int XPC = (SPLIT == 2) ? 2 : 4;   // XCDs per (batch,half) combo
    const int combo = xcd / XPC;
    const int batch = (SPLIT == 2) ? (combo >> 1) : combo;
    const int half  = (SPLIT == 2) ? (combo & 1) : 0;
    const int qbl   = (B >> 3) * XPC + (xcd % XPC);   // 0..63
    const int R0    = batch * SEQ + qbl * 128;        // absolute row base

    const int t    = threadIdx.x;
    const int lane = t & 63;
    const int w    = t >> 6;          // 0..7
    const int lr   = lane & 15;
    const int lkg  = lane >> 4;

    __shared__ _Float16 Klds[2][32][512];   // rows XOR-swizzled in 16B chunks
    __shared__ _Float16 Vlds[2][512][32];   // V^T: [d][kv], 64B rows
    __shared__ _Float16 Plds[128][40];      // P [q][kv], stride 40 (16B-aligned)
    __shared__ float    Scl[128];

    const _Float16* Qb = Qh + (size_t)batch * SEQ * DIMD;
    const _Float16* Vb = Vt + (size_t)batch * DIMD * SEQ;

    // role-Q fragments: wave's 16 rows x 512
    const int qrow = R0 + w * 16 + lr;
    f16x8 qf[16];
    #pragma unroll
    for (int ks = 0; ks < 16; ks++)
        qf[ks] = *(const f16x8*)(Kh + (size_t)qrow * DIMD + ks * 32 + lkg * 8);

    f32x4 Oacc[8][4] = {};    // [m-tile of 128 rows][n-tile of 64-wide d slice]
    float m_[4], l_[4];
    #pragma unroll
    for (int j = 0; j < 4; j++) { m_[j] = -1e30f; l_[j] = 0.f; }

    const int t0base = half * (SEQ / SPLIT);
    const int NT = (SEQ / SPLIT) / 32;

    // stage tile `it` into buffer `bf`: 4 K-rows + 4 V-d-blocks per wave
    #define STAGE(it, bfi)                                                     \
    {                                                                          \
        const int t0s = t0base + (it) * 32;                                    \
        _Pragma("unroll")                                                      \
        for (int i = 0; i < 4; i++) {                                          \
            const int r = w * 4 + i;                                           \
            const char* srcK = (const char*)(Qb + (size_t)(t0s + r) * DIMD)    \
                               + ((lane * 16) ^ ((r & 7) << 4));               \
            GLOAD16(srcK, (char*)&Klds[bfi][r][0]);                            \
        }                                                                      \
        _Pragma("unroll")                                                      \
        for (int i = 0; i < 4; i++) {                                          \
            const int d0 = (w * 4 + i) * 16;                                   \
            const _Float16* srcV = Vb + (size_t)(d0 + (lane >> 2)) * SEQ       \
                                   + t0s + 8 * (lane & 3);                     \
            GLOAD16(srcV, (char*)&Vlds[bfi][d0][0]);                           \
        }                                                                      \
    }

    STAGE(0, 0);
    asm volatile("s_waitcnt vmcnt(0)" ::: "memory");
    __builtin_amdgcn_s_barrier();
    asm volatile("" ::: "memory");

    for (int it = 0; it < NT; ++it) {
        const int cur = it & 1;
        if (it + 1 < NT) STAGE(it + 1, cur ^ 1);   // async into other buffer

        // ---- QK^T: wave's 16 rows x 32 kv ----
        f32x4 s0v = {}, s1v = {};
        #pragma unroll
        for (int ks = 0; ks < 16; ks++) {
            const int ch = (((ks * 4 + lkg) ^ (lr & 7)) << 4);
            f16x8 b0 = *(const f16x8*)((const char*)&Klds[cur][lr][0] + ch);
            f16x8 b1 = *(const f16x8*)((const char*)&Klds[cur][lr + 16][0] + ch);
            s0v = MFMA16(qf[ks], b0, s0v);
            s1v = MFMA16(qf[ks], b1, s1v);
        }

        // ---- online softmax (rows = 16w + 4*lkg + j, reduce across lr) ----
        float tm[4];
        #pragma unroll
        for (int j = 0; j < 4; j++) tm[j] = fmaxf(s0v[j], s1v[j]);
        #pragma unroll
        for (int off = 1; off < 16; off <<= 1)
            #pragma unroll
            for (int j = 0; j < 4; j++)
                tm[j] = fmaxf(tm[j], __shfl_xor(tm[j], off, 64));

        float pr0[4], pr1[4], scale[4], ps[4];
        #pragma unroll
        for (int j = 0; j < 4; j++) {
            float nm = fmaxf(m_[j], tm[j]);
            scale[j] = __expf(m_[j] - nm);
            m_[j] = nm;
            pr0[j] = __expf(s0v[j] - nm);
            pr1[j] = __expf(s1v[j] - nm);
            ps[j] = pr0[j] + pr1[j];
        }
        #pragma unroll
        for (int off = 1; off < 16; off <<= 1)
            #pragma unroll
            for (int j = 0; j < 4; j++)
                ps[j] += __shfl_xor(ps[j], off, 64);
        #pragma unroll
        for (int j = 0; j < 4; j++) l_[j] = l_[j] * scale[j] + ps[j];

        // share P (fp16) and per-row scale
        #pragma unroll
        for (int j = 0; j < 4; j++) {
            Plds[16 * w + 4 * lkg + j][lr]      = (_Float16)pr0[j];
            Plds[16 * w + 4 * lkg + j][lr + 16] = (_Float16)pr1[j];
        }
        if (lr == 0) {
            #pragma unroll
            for (int j = 0; j < 4; j++) Scl[16 * w + 4 * lkg + j] = scale[j];
        }

        // ---- MID barrier: P/Scl visible. NO vmcnt drain (stage in flight) ----
        asm volatile("s_waitcnt lgkmcnt(0)" ::: "memory");
        __builtin_amdgcn_s_barrier();
        asm volatile("" ::: "memory");

        // ---- rescale O (rows = m*16 + lkg*4 + r) ----
        float sc[8][4]; int needv = 0;
        #pragma unroll
        for (int m = 0; m < 8; m++) {
            f32x4 s4 = *(const f32x4*)&Scl[m * 16 + lkg * 4];
            #pragma unroll
            for (int r = 0; r < 4; r++) { sc[m][r] = s4[r]; needv |= (s4[r] != 1.f); }
        }
        if (__any(needv)) {
            #pragma unroll
            for (int m = 0; m < 8; m++)
                #pragma unroll
                for (int n = 0; n < 4; n++)
                    #pragma unroll
                    for (int r = 0; r < 4; r++) Oacc[m][n][r] *= sc[m][r];
        }

        // ---- PV: O[128 q][d-slice 64w..] += P[128x32] @ V[32 x 64] ----
        f16x8 vbf[4];
        #pragma unroll
        for (int n = 0; n < 4; n++)
            vbf[n] = *(const f16x8*)&Vlds[cur][w * 64 + n * 16 + lr][lkg * 8];
        #pragma unroll
        for (int m = 0; m < 8; m++) {
            f16x8 pa = *(const f16x8*)&Plds[m * 16 + lr][lkg * 8];
            #pragma unroll
            for (int n = 0; n < 4; n++)
                Oacc[m][n] = MFMA16(pa, vbf[n], Oacc[m][n]);
        }

        // ---- END barrier: staged tile landed; all reads of cur done ----
        asm volatile("s_waitcnt vmcnt(0) lgkmcnt(0)" ::: "memory");
        __builtin_amdgcn_s_barrier();
        asm volatile("" ::: "memory");
    }

    // ---- share 1/l (and m,l for SPLIT), normalize, store ----
    if (lr == 0) {
        #pragma unroll
        for (int j = 0; j < 4; j++) Scl[16 * w + 4 * lkg + j] = 1.f / l_[j];
        if (SPLIT > 1) {
            #pragma unroll
            for (int j = 0; j < 4; j++) {
                int R = R0 + 16 * w + 4 * lkg + j;
                Ml[((size_t)half * MTOT + R) * 2]     = m_[j];
                Ml[((size_t)half * MTOT + R) * 2 + 1] = l_[j];
            }
        }
    }
    asm volatile("s_waitcnt lgkmcnt(0)" ::: "memory");
    __builtin_amdgcn_s_barrier();
    asm volatile("" ::: "memory");

    float li[8][4];
    #pragma unroll
    for (int m = 0; m < 8; m++) {
        f32x4 s4 = *(const f32x4*)&Scl[m * 16 + lkg * 4];
        #pragma unroll
        for (int r = 0; r < 4; r++) li[m][r] = s4[r];
    }
    #pragma unroll
    for (int m = 0; m < 8; m++) {
        #pragma unroll
        for (int n = 0; n < 4; n++) {
            #pragma unroll
            for (int r = 0; r < 4; r++) {
                float val = Oacc[m][n][r] * li[m][r];
                int R = R0 + m * 16 + lkg * 4 + r;
                int d = w * 64 + n * 16 + lr;
                if (SPLIT == 1) {
                    out[(size_t)R * DIMD + d] = val;
                } else {
                    Opart[((size_t)half * MTOT + R) * DIMD + d] = (_Float16)val;
                }
            }
        }
    }
    #undef STAGE
}

// ---------------------------------------------------------------------------
// Combine the SPLIT=2 halves: out = (a0*O0 + a1*O1), a_h = e^{m_h-M} l_h / Z
// ---------------------------------------------------------------------------
__global__ __launch_bounds__(256) void combine_kernel(
    const _Float16* __restrict__ Opart, const float* __restrict__ Ml,
    float* __restrict__ out)
{
    size_t idx = (size_t)blockIdx.x * 256 + threadIdx.x;
    size_t e0 = idx * 8;
    int R = (int)(e0 >> 9);
    float m0 = Ml[(size_t)R * 2],            l0 = Ml[(size_t)R * 2 + 1];
    float m1 = Ml[((size_t)MTOT + R) * 2],   l1 = Ml[((size_t)MTOT + R) * 2 + 1];
    float M  = fmaxf(m0, m1);
    float a0 = __expf(m0 - M) * l0;
    float a1 = __expf(m1 - M) * l1;
    float inv = 1.f / (a0 + a1);
    a0 *= inv; a1 *= inv;
    f16x8 o0 = *(const f16x8*)(Opart + e0);
    f16x8 o1 = *(const f16x8*)(Opart + (size_t)MTOT * DIMD + e0);
    f32x4 r0, r1;
    #pragma unroll
    for (int u = 0; u < 4; u++) r0[u] = a0 * (float)o0[u] + a1 * (float)o1[u];
    #pragma unroll
    for (int u = 0; u < 4; u++) r1[u] = a0 * (float)o0[u + 4] + a1 * (float)o1[u + 4];
    *(f32x4*)(out + e0) = r0;
    *(f32x4*)(out + e0 + 4) = r1;
}

extern "C" void kernel_launch(void* const* d_in, const int* in_sizes, int n_in,
                              void* d_out, int out_size, void* d_ws, size_t ws_size,
                              hipStream_t stream) {
    (void)in_sizes; (void)n_in; (void)out_size;
    const float* x1 = (const float*)d_in[0];
    const float* Wk = (const float*)d_in[1];
    const float* bk = (const float*)d_in[2];
    const float* Wq = (const float*)d_in[3];
    const float* bq = (const float*)d_in[4];
    const float* Wv = (const float*)d_in[5];
    const float* bv = (const float*)d_in[6];
    float* out = (float*)d_out;

    _Float16* Kh = (_Float16*)d_ws;
    _Float16* Qh = Kh + (size_t)MTOT * DIMD;
    _Float16* Vt = Qh + (size_t)MTOT * DIMD;

    const size_t base = (size_t)MTOT * DIMD * 2 * 3;   // 48 MB
    const size_t opart_bytes = (size_t)2 * MTOT * DIMD * sizeof(_Float16); // 32 MB
    const size_t need2 = base + opart_bytes + (size_t)2 * MTOT * 2 * sizeof(float);
    _Float16* Opart = (_Float16*)((char*)d_ws + base);
    float*    Ml    = (float*)((char*)d_ws + base + opart_bytes);
    const int split2 = (ws_size >= need2);

    // mask output: 16 zero floats after the attention output
    hipMemsetAsync((char*)d_out + (size_t)MTOT * DIMD * sizeof(float), 0, 64, stream);

    dim3 pg(128, 4, 3);
    proj_kernel<<<pg, 256, 0, stream>>>(x1, Wk, bk, Wq, bq, Wv, bv, Kh, Qh, Vt);

    if (split2) {
        flash_kernel<2><<<dim3(256), 512, 0, stream>>>(Kh, Qh, Vt, out, Opart, Ml);
        combine_kernel<<<4096, 256, 0, stream>>>(Opart, Ml, out);
    } else {
        flash_kernel<1><<<dim3(128), 512, 0, stream>>>(Kh, Qh, Vt, out, Opart, Ml);
    }
}